// Round 6
// baseline (81.553 us; speedup 1.0000x reference)
//
#include <hip/hip_runtime.h>

typedef __attribute__((ext_vector_type(8))) short bf16x8;
typedef __attribute__((ext_vector_type(4))) float f32x4;

#define GAMMA_ 0.5f
#define LOG2E_ 1.4426950408889634f

constexpr int D      = 256;   // feature dim (K)
constexpr int BM     = 256;   // rows of X per block (4 waves x 64)
constexpr int WN     = 32;    // cols per wave tile (j-tile width)
constexpr int JSPLIT = 16;    // split of M across blockIdx.y

// ---------- helpers ----------
__device__ __forceinline__ unsigned short f2bf(float f) {
    unsigned int x = __float_as_uint(f);
    x += 0x7FFFu + ((x >> 16) & 1u);          // RNE
    return (unsigned short)(x >> 16);
}

// ---------- prep: cast to bf16, row |x|^2, coefs, out-init ----------
__global__ void prep_all_kernel(const float* __restrict__ X,
                                const float* __restrict__ Xt,
                                const float* __restrict__ alphas,
                                const float* __restrict__ y,
                                const float* __restrict__ b,
                                unsigned short* __restrict__ Abf,
                                unsigned short* __restrict__ Bbf,
                                float* __restrict__ srow,
                                float* __restrict__ tcol,
                                float* __restrict__ coef,
                                float* __restrict__ out,
                                int N, int M) {
    int w = threadIdx.x >> 6;         // one wave per row
    int l = threadIdx.x & 63;
    int row = blockIdx.x * 4 + w;
    if (row >= N + M) return;
    const float* src;
    unsigned short* dst;
    if (row < N) { src = X  + (size_t)row * D;       dst = Abf + (size_t)row * D; }
    else         { src = Xt + (size_t)(row - N) * D; dst = Bbf + (size_t)(row - N) * D; }
    const float4 v = reinterpret_cast<const float4*>(src)[l];
    ushort4 u;
    u.x = f2bf(v.x); u.y = f2bf(v.y); u.z = f2bf(v.z); u.w = f2bf(v.w);
    reinterpret_cast<ushort4*>(dst)[l] = u;
    float ss = v.x * v.x + v.y * v.y + v.z * v.z + v.w * v.w;
    #pragma unroll
    for (int off = 32; off >= 1; off >>= 1) ss += __shfl_xor(ss, off);
    if (l == 0) {
        float folded = -GAMMA_ * LOG2E_ * ss;
        if (row < N) { srow[row] = folded; out[row] = b[0]; }
        else {
            int r2 = row - N;
            tcol[r2] = folded;
            coef[r2] = alphas[r2] * y[r2];
        }
    }
}

// ---------- fused RBF-SVM predict: barrier-free, LDS-free ----------
// Each wave: A strip (64 rows x K=256) in registers; B fragments gathered
// directly from global (L1/L2-resident), double-buffered in registers.
// pred_i = sum_j exp2( s_i + t_j + (2*g*log2e) * <x_i, xt_j> ) * coef_j + b
__launch_bounds__(256, 2)
__global__ void svm_main_kernel(const unsigned short* __restrict__ Abf,
                                const unsigned short* __restrict__ Bbf,
                                const float* __restrict__ srow,
                                const float* __restrict__ tcol,
                                const float* __restrict__ coef,
                                float* __restrict__ out,
                                int M) {
    const int tid = threadIdx.x;
    const int w   = tid >> 6;          // wave 0..3 (stacked in M)
    const int l   = tid & 63;
    const int hi  = l >> 4;            // 0..3
    const int lo  = l & 15;
    const int row0w  = blockIdx.x * BM + w * 64;   // this wave's A rows
    const int jspan  = M / JSPLIT;                 // 512
    const int jbase  = blockIdx.y * jspan;
    const int JT     = jspan / WN;                 // 16 j-tiles per wave

    const char* Ab = (const char*)Abf;
    const char* Bb = (const char*)Bbf + (size_t)jbase * 512;

    // per-lane loop-invariant byte offsets for the 4 B-loads of a stage
    // idx = ni*2+ks : row (ni*16+lo), bytes [ks*64 + hi*16 .. +16)
    int boff[4];
    #pragma unroll
    for (int ni = 0; ni < 2; ++ni)
        #pragma unroll
        for (int ks = 0; ks < 2; ++ks)
            boff[ni * 2 + ks] = (ni * 16 + lo) * 512 + ks * 64 + hi * 16;

    // ---- A strip into registers (held whole kernel): 128 VGPR ----
    bf16x8 areg[4][8];
    #pragma unroll
    for (int mi = 0; mi < 4; ++mi) {
        int row = row0w + mi * 16 + lo;
        #pragma unroll
        for (int kg = 0; kg < 8; ++kg)
            areg[mi][kg] = *(const bf16x8*)(Ab + (size_t)row * 512 + kg * 64 + hi * 16);
    }

    // per-lane row constants
    float sreg[4][4];
    #pragma unroll
    for (int mi = 0; mi < 4; ++mi)
        #pragma unroll
        for (int r = 0; r < 4; ++r)
            sreg[mi][r] = srow[row0w + mi * 16 + hi * 4 + r];

    float partial[4][4];
    #pragma unroll
    for (int mi = 0; mi < 4; ++mi)
        #pragma unroll
        for (int r = 0; r < 4; ++r) partial[mi][r] = 0.0f;

#define LOADB(V, JT2, KT2)                                                     \
    {                                                                          \
        const char* p_ = Bb + (size_t)(JT2) * (WN * 512) + (KT2) * 128;        \
        V[0] = *(const bf16x8*)(p_ + boff[0]);                                 \
        V[1] = *(const bf16x8*)(p_ + boff[1]);                                 \
        V[2] = *(const bf16x8*)(p_ + boff[2]);                                 \
        V[3] = *(const bf16x8*)(p_ + boff[3]);                                 \
    }

#define MMA(V, KT2)                                                            \
    {                                                                          \
        _Pragma("unroll")                                                      \
        for (int mi = 0; mi < 4; ++mi) {                                       \
            acc[mi][0] = __builtin_amdgcn_mfma_f32_16x16x32_bf16(              \
                areg[mi][(KT2) * 2 + 0], V[0], acc[mi][0], 0, 0, 0);           \
            acc[mi][1] = __builtin_amdgcn_mfma_f32_16x16x32_bf16(              \
                areg[mi][(KT2) * 2 + 0], V[2], acc[mi][1], 0, 0, 0);           \
            acc[mi][0] = __builtin_amdgcn_mfma_f32_16x16x32_bf16(              \
                areg[mi][(KT2) * 2 + 1], V[1], acc[mi][0], 0, 0, 0);           \
            acc[mi][1] = __builtin_amdgcn_mfma_f32_16x16x32_bf16(              \
                areg[mi][(KT2) * 2 + 1], V[3], acc[mi][1], 0, 0, 0);           \
        }                                                                      \
    }

    const float K2G = 2.0f * GAMMA_ * LOG2E_;

    bf16x8 bE[4], bO[4];
    LOADB(bE, 0, 0);   // prologue: stage (0,0) in flight

    for (int jt = 0; jt < JT; ++jt) {
        f32x4 acc[4][2];
        #pragma unroll
        for (int mi = 0; mi < 4; ++mi)
            #pragma unroll
            for (int ni = 0; ni < 2; ++ni) {
                f32x4 z = {0.f, 0.f, 0.f, 0.f};
                acc[mi][ni] = z;
            }

        // column constants issued early (hide under kt0's MFMA)
        int colg = jbase + jt * WN + lo;
        float t0 = tcol[colg],      c0 = coef[colg];
        float t1 = tcol[colg + 16], c1 = coef[colg + 16];

        // 4 K-steps, B double-buffered one stage ahead, no sync anywhere
        LOADB(bO, jt, 1);
        MMA(bE, 0);
        LOADB(bE, jt, 2);
        MMA(bO, 1);
        LOADB(bO, jt, 3);
        MMA(bE, 2);
        if (jt + 1 < JT) LOADB(bE, jt + 1, 0);
        MMA(bO, 3);

        // ---- fused epilogue: exp2 + weighted row-accumulate ----
        #pragma unroll
        for (int mi = 0; mi < 4; ++mi) {
            #pragma unroll
            for (int r = 0; r < 4; ++r) {
                float base = sreg[mi][r];
                float a0 = fmaf(acc[mi][0][r], K2G, base + t0);
                float a1 = fmaf(acc[mi][1][r], K2G, base + t1);
                float p0 = __builtin_amdgcn_exp2f(a0);
                float p1 = __builtin_amdgcn_exp2f(a1);
                partial[mi][r] = fmaf(p0, c0, fmaf(p1, c1, partial[mi][r]));
            }
        }
    }
#undef LOADB
#undef MMA

    // ---- reduce across the 16 lanes of each row group, one atomic per row ----
    #pragma unroll
    for (int mi = 0; mi < 4; ++mi) {
        #pragma unroll
        for (int r = 0; r < 4; ++r) {
            float v = partial[mi][r];
            v += __shfl_xor(v, 1);
            v += __shfl_xor(v, 2);
            v += __shfl_xor(v, 4);
            v += __shfl_xor(v, 8);
            if (lo == 0) {
                int rowg = row0w + mi * 16 + hi * 4 + r;
                atomicAdd(&out[rowg], v);
            }
        }
    }
}

// ---------- launcher ----------
extern "C" void kernel_launch(void* const* d_in, const int* in_sizes, int n_in,
                              void* d_out, int out_size, void* d_ws, size_t ws_size,
                              hipStream_t stream) {
    const float* X      = (const float*)d_in[0];
    const float* Xt     = (const float*)d_in[1];
    const float* alphas = (const float*)d_in[2];
    const float* y      = (const float*)d_in[3];
    const float* b      = (const float*)d_in[4];
    float* out = (float*)d_out;

    const int N = in_sizes[0] / D;   // 8192
    const int M = in_sizes[1] / D;   // 8192

    // workspace: bf16 X | bf16 Xt | srow[N] | tcol[M] | coef[M]
    char* ws = (char*)d_ws;
    unsigned short* Abf = (unsigned short*)ws;
    unsigned short* Bbf = Abf + (size_t)N * D;
    float* srow = (float*)(Bbf + (size_t)M * D);
    float* tcol = srow + N;
    float* coef = tcol + M;

    prep_all_kernel<<<(N + M) / 4, 256, 0, stream>>>(X, Xt, alphas, y, b,
                                                     Abf, Bbf, srow, tcol, coef,
                                                     out, N, M);

    dim3 grid(N / BM, JSPLIT);
    svm_main_kernel<<<grid, 256, 0, stream>>>(Abf, Bbf, srow, tcol, coef, out, M);
}

// Round 7
// 51.758 us; speedup vs baseline: 1.5757x; 1.5757x over previous
//
#include <hip/hip_runtime.h>

typedef __attribute__((ext_vector_type(8))) short bf16x8;
typedef __attribute__((ext_vector_type(4))) float f32x4;

#define GAMMA_ 0.5f
#define LOG2E_ 1.4426950408889634f

constexpr int D      = 256;   // feature dim (K)
constexpr int BM     = 128;   // rows of X per block (2 row-groups of 64)
constexpr int BN     = 64;    // cols per B stage tile
constexpr int JSPLIT = 8;     // split of M across blockIdx.y

// LDS layout (bytes): ring 4 x 8KB | tcol 4KB | coef 4KB
constexpr int AUX_TCOL  = 32768;
constexpr int AUX_COEF  = 36864;
constexpr int LDS_BYTES = 40960;

// ---------- helpers ----------
__device__ __forceinline__ unsigned short f2bf(float f) {
    unsigned int x = __float_as_uint(f);
    x += 0x7FFFu + ((x >> 16) & 1u);          // RNE
    return (unsigned short)(x >> 16);
}

__device__ __forceinline__ void gload16(void* lds, const void* g) {
    __builtin_amdgcn_global_load_lds(
        (const __attribute__((address_space(1))) void*)g,
        (__attribute__((address_space(3))) void*)lds, 16, 0, 0);
}

// ---------- prep: cast to bf16, row |x|^2, coefs, out-init ----------
__global__ void prep_all_kernel(const float* __restrict__ X,
                                const float* __restrict__ Xt,
                                const float* __restrict__ alphas,
                                const float* __restrict__ y,
                                const float* __restrict__ b,
                                unsigned short* __restrict__ Abf,
                                unsigned short* __restrict__ Bbf,
                                float* __restrict__ srow,
                                float* __restrict__ tcol,
                                float* __restrict__ coef,
                                float* __restrict__ out,
                                int N, int M) {
    int w = threadIdx.x >> 6;         // one wave per row
    int l = threadIdx.x & 63;
    int row = blockIdx.x * 4 + w;
    if (row >= N + M) return;
    const float* src;
    unsigned short* dst;
    if (row < N) { src = X  + (size_t)row * D;       dst = Abf + (size_t)row * D; }
    else         { src = Xt + (size_t)(row - N) * D; dst = Bbf + (size_t)(row - N) * D; }
    const float4 v = reinterpret_cast<const float4*>(src)[l];
    ushort4 u;
    u.x = f2bf(v.x); u.y = f2bf(v.y); u.z = f2bf(v.z); u.w = f2bf(v.w);
    reinterpret_cast<ushort4*>(dst)[l] = u;
    float ss = v.x * v.x + v.y * v.y + v.z * v.z + v.w * v.w;
    #pragma unroll
    for (int off = 32; off >= 1; off >>= 1) ss += __shfl_xor(ss, off);
    if (l == 0) {
        float folded = -GAMMA_ * LOG2E_ * ss;
        if (row < N) { srow[row] = folded; out[row] = b[0]; }
        else {
            int r2 = row - N;
            tcol[r2] = folded;
            coef[r2] = alphas[r2] * y[r2];
        }
    }
}

// ---------- fused RBF-SVM predict ----------
// pred_i = sum_j exp2( s_i + t_j + (2*g*log2e) * <x_i, xt_j> ) * coef_j + b
// 4 waves; wave (wr,wc) owns rows [wr*64,+64) x cols [wc*32,+32) of each tile.
// A strip in registers; B staged via 4-slot global_load_lds ring, 3 in flight.
__launch_bounds__(256, 2)
__global__ void svm_main_kernel(const unsigned short* __restrict__ Abf,
                                const unsigned short* __restrict__ Bbf,
                                const float* __restrict__ srow,
                                const float* __restrict__ tcol,
                                const float* __restrict__ coef,
                                float* __restrict__ out,
                                int M) {
    __shared__ char L[LDS_BYTES];

    const int tid = threadIdx.x;
    const int w   = tid >> 6;          // wave 0..3
    const int l   = tid & 63;
    const int wr  = w >> 1;            // row group 0..1
    const int wc  = w & 1;             // col group 0..1 (disjoint cols!)
    const int hi  = l >> 4;            // 0..3
    const int lo  = l & 15;
    const int row0   = blockIdx.x * BM;
    const int jspan  = M / JSPLIT;     // 1024
    const int jbase  = blockIdx.y * jspan;
    const int JT     = jspan / BN;     // 16 j-tiles -> 64 stages per block

    // ---- aux staging (tcol/coef slices -> LDS; keeps vmcnt queue clean) ----
    gload16(L + AUX_TCOL + w * 1024, (const char*)(tcol + jbase) + tid * 16);
    gload16(L + AUX_COEF + w * 1024, (const char*)(coef + jbase) + tid * 16);

    // ---- per-lane row constants from global (pre-loop; outside vmcnt region) ----
    float sreg[4][4];
    #pragma unroll
    for (int mi = 0; mi < 4; ++mi)
        #pragma unroll
        for (int r = 0; r < 4; ++r)
            sreg[mi][r] = srow[row0 + wr * 64 + mi * 16 + hi * 4 + r];

    // ---- A strip into registers (held whole kernel): 128 VGPR ----
    const char* Ab = (const char*)Abf;
    bf16x8 areg[4][8];
    #pragma unroll
    for (int mi = 0; mi < 4; ++mi) {
        int row = row0 + wr * 64 + mi * 16 + lo;
        #pragma unroll
        for (int kg = 0; kg < 8; ++kg)
            areg[mi][kg] = *(const bf16x8*)(Ab + (size_t)row * 512 + kg * 64 + hi * 16);
    }

    // ---- B ring staging: 8 KiB/stage, 2 gload16/thread ----
    const char* Bb = (const char*)Bbf + (size_t)jbase * 512;
    auto issueB = [&](int jt2, int kt2, int slot) {
        #pragma unroll
        for (int c = 0; c < 2; ++c) {
            int x   = c * 4096 + tid * 16;
            int col = x >> 7;                        // 128 B per (col, kt) row
            int src = (jt2 * BN + col) * 512 + kt2 * 128
                    + ((x & 127) ^ ((col & 7) << 4));
            gload16(L + slot * 8192 + c * 4096 + w * 1024, Bb + src);
        }
    };
    issueB(0, 0, 0);
    issueB(0, 1, 1);
    issueB(0, 2, 2);   // 6 B-loads outstanding (3 stages deep)

    float partial[4][4];
    #pragma unroll
    for (int mi = 0; mi < 4; ++mi)
        #pragma unroll
        for (int r = 0; r < 4; ++r) partial[mi][r] = 0.0f;

    const float K2G = 2.0f * GAMMA_ * LOG2E_;

    for (int jt = 0; jt < JT; ++jt) {
        f32x4 acc[4][2];
        #pragma unroll
        for (int mi = 0; mi < 4; ++mi)
            #pragma unroll
            for (int ni = 0; ni < 2; ++ni) {
                f32x4 z = {0.f, 0.f, 0.f, 0.f};
                acc[mi][ni] = z;
            }

        #pragma unroll
        for (int kt = 0; kt < 4; ++kt) {             // stage s = jt*4 + kt
            const int slot = kt;                     // ring slot = s & 3
            const int jt2 = jt + ((kt + 3) >> 2);    // issue stage s+3
            const int kt2 = (kt + 3) & 3;
            if (jt2 < JT) {
                issueB(jt2, kt2, (kt + 3) & 3);
                asm volatile("s_waitcnt vmcnt(6)" ::: "memory");  // stage s done
            } else if (kt == 1) {
                asm volatile("s_waitcnt vmcnt(4)" ::: "memory");
            } else if (kt == 2) {
                asm volatile("s_waitcnt vmcnt(2)" ::: "memory");
            } else {
                asm volatile("s_waitcnt vmcnt(0)" ::: "memory");
            }
            __builtin_amdgcn_s_barrier();            // stage-s B visible to all

            bf16x8 bb[2][2];
            #pragma unroll
            for (int ni = 0; ni < 2; ++ni) {
                int col = wc * 32 + ni * 16 + lo;    // disjoint per wc
                #pragma unroll
                for (int ks = 0; ks < 2; ++ks) {
                    int off = slot * 8192 + col * 128
                            + ((ks * 64 + hi * 16) ^ ((col & 7) << 4));
                    bb[ni][ks] = *(const bf16x8*)(L + off);
                }
            }
            __builtin_amdgcn_s_setprio(1);
            #pragma unroll
            for (int ks = 0; ks < 2; ++ks)
                #pragma unroll
                for (int mi = 0; mi < 4; ++mi)
                    #pragma unroll
                    for (int ni = 0; ni < 2; ++ni)
                        acc[mi][ni] = __builtin_amdgcn_mfma_f32_16x16x32_bf16(
                            areg[mi][kt * 2 + ks], bb[ni][ks], acc[mi][ni], 0, 0, 0);
            __builtin_amdgcn_s_setprio(0);
            __builtin_amdgcn_s_barrier();            // all reads of slot done
        }

        // ---- fused epilogue: exp2 + weighted row-accumulate (LDS aux reads) ----
        #pragma unroll
        for (int ni = 0; ni < 2; ++ni) {
            int cl = jt * BN + wc * 32 + ni * 16 + lo;
            float t  = *(const float*)(L + AUX_TCOL + cl * 4);
            float cf = *(const float*)(L + AUX_COEF + cl * 4);
            #pragma unroll
            for (int mi = 0; mi < 4; ++mi) {
                #pragma unroll
                for (int r = 0; r < 4; ++r) {
                    float arg = fmaf(acc[mi][ni][r], K2G, sreg[mi][r] + t);
                    float p = __builtin_amdgcn_exp2f(arg);
                    partial[mi][r] = fmaf(p, cf, partial[mi][r]);
                }
            }
        }
    }

    // ---- reduce across the 16 lanes of each row group, one atomic per row ----
    #pragma unroll
    for (int mi = 0; mi < 4; ++mi) {
        #pragma unroll
        for (int r = 0; r < 4; ++r) {
            float v = partial[mi][r];
            v += __shfl_xor(v, 1);
            v += __shfl_xor(v, 2);
            v += __shfl_xor(v, 4);
            v += __shfl_xor(v, 8);
            if (lo == 0) {
                int rowg = row0 + wr * 64 + mi * 16 + hi * 4 + r;
                atomicAdd(&out[rowg], v);
            }
        }
    }
}

// ---------- launcher ----------
extern "C" void kernel_launch(void* const* d_in, const int* in_sizes, int n_in,
                              void* d_out, int out_size, void* d_ws, size_t ws_size,
                              hipStream_t stream) {
    const float* X      = (const float*)d_in[0];
    const float* Xt     = (const float*)d_in[1];
    const float* alphas = (const float*)d_in[2];
    const float* y      = (const float*)d_in[3];
    const float* b      = (const float*)d_in[4];
    float* out = (float*)d_out;

    const int N = in_sizes[0] / D;   // 8192
    const int M = in_sizes[1] / D;   // 8192

    // workspace: bf16 X | bf16 Xt | srow[N] | tcol[M] | coef[M]
    char* ws = (char*)d_ws;
    unsigned short* Abf = (unsigned short*)ws;
    unsigned short* Bbf = Abf + (size_t)N * D;
    float* srow = (float*)(Bbf + (size_t)M * D);
    float* tcol = srow + N;
    float* coef = tcol + M;

    prep_all_kernel<<<(N + M) / 4, 256, 0, stream>>>(X, Xt, alphas, y, b,
                                                     Abf, Bbf, srow, tcol, coef,
                                                     out, N, M);

    dim3 grid(N / BM, JSPLIT);
    svm_main_kernel<<<grid, 256, 0, stream>>>(Abf, Bbf, srow, tcol, coef, out, M);
}